// Round 2
// baseline (43.186 us; speedup 1.0000x reference)
//
#include <hip/hip_runtime.h>

// Problem constants (from reference)
#define LIN   4096
#define LOUT  4097          // (L + 2*PAD - KERNEL) + 1
#define NCH   8
#define NBS   16
#define POS_PER_BLK 16      // positions per 128-thread block (16 groups of 8 ch)
#define PB    257           // ceil(LOUT / POS_PER_BLK)

// d_ws float layout:
//  [0..63]    M[b][q] atomic-max targets (relu'd -> uint order == float order)
//  [64..71]   cos(w/2) for layers 1,2 (4 qubits each)
//  [72..79]   sin(w/2) for layers 1,2
//  [80..95]   Re(state) after basic_layer(weights[0]) on |0000>
//  [96..111]  Im(state)

// ---------------- register statevector gates (fully unrolled) ----------------
// State index: qubit j <-> bit (8 >> j); q0 is MSB (matches jnp C-order flatten).

template<int BIT>
__device__ __forceinline__ void apply_rx(float sr[16], float si[16], float c, float s) {
#pragma unroll
  for (int k = 0; k < 16; ++k) {
    if ((k & BIT) == 0) {
      const int a = k, b = k | BIT;
      const float ar = sr[a], ai = si[a], br = sr[b], bi = si[b];
      sr[a] = c * ar + s * bi;
      si[a] = c * ai - s * br;
      sr[b] = c * br + s * ai;
      si[b] = c * bi - s * ar;
    }
  }
}

template<int BIT>
__device__ __forceinline__ void apply_ry(float sr[16], float si[16], float c, float s) {
#pragma unroll
  for (int k = 0; k < 16; ++k) {
    if ((k & BIT) == 0) {
      const int a = k, b = k | BIT;
      const float ar = sr[a], ai = si[a], br = sr[b], bi = si[b];
      sr[a] = c * ar - s * br;
      si[a] = c * ai - s * bi;
      sr[b] = s * ar + c * br;
      si[b] = s * ai + c * bi;
    }
  }
}

// RY on qubit 0 (bit 8) reading from (possibly SGPR-resident) src state
__device__ __forceinline__ void apply_ry_q0_src(float sr[16], float si[16],
                                                const float r0[16], const float i0[16],
                                                float c, float s) {
#pragma unroll
  for (int k = 0; k < 8; ++k) {
    const int a = k, b = k | 8;
    sr[a] = c * r0[a] - s * r0[b];
    si[a] = c * i0[a] - s * i0[b];
    sr[b] = s * r0[a] + c * r0[b];
    si[b] = s * i0[a] + c * i0[b];
  }
}

template<int CBIT, int TBIT>
__device__ __forceinline__ void apply_cnot(float sr[16], float si[16]) {
#pragma unroll
  for (int k = 0; k < 16; ++k) {
    if ((k & CBIT) != 0 && (k & TBIT) == 0) {
      const int a = k, b = k | TBIT;
      float t;
      t = sr[a]; sr[a] = sr[b]; sr[b] = t;
      t = si[a]; si[a] = si[b]; si[b] = t;
    }
  }
}

__device__ __forceinline__ void basic_layer(float sr[16], float si[16],
                                            const float c[4], const float s[4]) {
  apply_rx<8>(sr, si, c[0], s[0]);
  apply_rx<4>(sr, si, c[1], s[1]);
  apply_rx<2>(sr, si, c[2], s[2]);
  apply_rx<1>(sr, si, c[3], s[3]);
  apply_cnot<8, 4>(sr, si);
  apply_cnot<4, 2>(sr, si);
  apply_cnot<2, 1>(sr, si);
  apply_cnot<1, 8>(sr, si);
}

__device__ __forceinline__ float rfl(float v) {
  return __int_as_float(__builtin_amdgcn_readfirstlane(__float_as_int(v)));
}

// ---------------- setup: trig of fixed weights + constant layer-0 state ----------------
__global__ __launch_bounds__(64) void setup_kernel(const float* __restrict__ weights,
                                                   float* __restrict__ ws) {
  const int tid = threadIdx.x;
  __shared__ float lc[4], ls[4];
  if (tid < 64) ws[tid] = 0.0f;  // zero atomic-max targets M (also needed: poison is 0xAA)
  if (tid < 12) {
    const int l = tid >> 2, q = tid & 3;
    float c, s;
    __sincosf(weights[tid] * 0.5f, &s, &c);
    if (l == 0) { lc[q] = c; ls[q] = s; }
    else {
      ws[64 + (l - 1) * 4 + q] = c;
      ws[72 + (l - 1) * 4 + q] = s;
    }
  }
  __syncthreads();
  if (tid == 0) {
    float sr[16], si[16];
#pragma unroll
    for (int k = 0; k < 16; ++k) { sr[k] = 0.0f; si[k] = 0.0f; }
    sr[0] = 1.0f;
    float c[4] = {lc[0], lc[1], lc[2], lc[3]};
    float s[4] = {ls[0], ls[1], ls[2], ls[3]};
    basic_layer(sr, si, c, s);
#pragma unroll
    for (int k = 0; k < 16; ++k) {
      ws[80 + k] = sr[k];
      ws[96 + k] = si[k];
    }
  }
}

// ---------------- main: one thread = one (b, ch, pos) circuit ----------------
__global__ __launch_bounds__(128, 8) void quanv_kernel(const float* __restrict__ x,
                                                       const float* __restrict__ ws,
                                                       float* __restrict__ wsM) {
  const int tid = threadIdx.x;
  const int blk = blockIdx.x;
  const int b   = blk / PB;
  const int pb  = blk - b * PB;
  const int ch  = tid & 7;
  const int grp = tid >> 3;                // 0..15
  const int pos = pb * POS_PER_BLK + grp;

  // window (PADDING=1): win[0] = x[pos-1], win[1] = x[pos]
  const float* row = x + (((size_t)b * NCH + ch) << 12);
  const float w0 = (pos >= 1 && pos <= LIN) ? row[pos - 1] : 0.0f;
  const float w1 = (pos < LIN) ? row[pos] : 0.0f;

  // uniform constants -> SGPRs via readfirstlane
  float uf[48];
  const float4* u = (const float4*)(ws + 64);
#pragma unroll
  for (int i = 0; i < 12; ++i) {
    const float4 t = u[i];
    uf[i * 4 + 0] = rfl(t.x);
    uf[i * 4 + 1] = rfl(t.y);
    uf[i * 4 + 2] = rfl(t.z);
    uf[i * 4 + 3] = rfl(t.w);
  }
  const float* c1w = uf;         // cos layer1 [4]
  const float* c2w = uf + 4;     // cos layer2 [4]
  const float* s1w = uf + 8;     // sin layer1 [4]
  const float* s2w = uf + 12;    // sin layer2 [4]
  const float* r0  = uf + 16;    // Re state after layer0 [16]
  const float* i0  = uf + 32;    // Im state after layer0 [16]

  float c0, s0, c1, s1;
  __sincosf(w0 * 0.5f, &s0, &c0);
  __sincosf(w1 * 0.5f, &s1, &c1);

  float sr[16], si[16];
  // data layer 1: RY(w0) q0, RY(w1) q1, RY(w0) q2, RY(w1) q3
  apply_ry_q0_src(sr, si, r0, i0, c0, s0);
  apply_ry<4>(sr, si, c1, s1);
  apply_ry<2>(sr, si, c0, s0);
  apply_ry<1>(sr, si, c1, s1);
  basic_layer(sr, si, c1w, s1w);

  // data layer 2
  apply_ry<8>(sr, si, c0, s0);
  apply_ry<4>(sr, si, c1, s1);
  apply_ry<2>(sr, si, c0, s0);
  apply_ry<1>(sr, si, c1, s1);
  basic_layer(sr, si, c2w, s2w);

  // probabilities + partial Walsh tree for the 4 single-qubit Z expectations
  float p[16];
#pragma unroll
  for (int k = 0; k < 16; ++k) p[k] = fmaf(sr[k], sr[k], si[k] * si[k]);

  float a1[8], ev3 = 0.0f;
#pragma unroll
  for (int k = 0; k < 8; ++k) {
    a1[k] = p[2 * k] + p[2 * k + 1];
    ev3 += p[2 * k] - p[2 * k + 1];
  }
  float a2[4], ev2 = 0.0f;
#pragma unroll
  for (int k = 0; k < 4; ++k) {
    a2[k] = a1[2 * k] + a1[2 * k + 1];
    ev2 += a1[2 * k] - a1[2 * k + 1];
  }
  const float ev1 = (a2[0] - a2[1]) + (a2[2] - a2[3]);
  const float ev0 = (a2[0] + a2[1]) - (a2[2] + a2[3]);

  float ev[4] = {ev0, ev1, ev2, ev3};
  // sum over channels: butterfly within 8-lane groups (tid = grp*8 + ch)
#pragma unroll
  for (int m = 1; m < 8; m <<= 1) {
#pragma unroll
    for (int q = 0; q < 4; ++q) ev[q] += __shfl_xor(ev[q], m, 64);
  }

  __shared__ float lmax[4][POS_PER_BLK];
  if (ch == 0) {
#pragma unroll
    for (int q = 0; q < 4; ++q)
      lmax[q][grp] = (pos < LOUT) ? fmaxf(ev[q], 0.0f) : 0.0f;
  }
  __syncthreads();
  if (tid < 4) {
    float m = 0.0f;
#pragma unroll
    for (int g = 0; g < POS_PER_BLK; ++g) m = fmaxf(m, lmax[tid][g]);
    atomicMax((unsigned int*)(wsM + b * 4 + tid), __float_as_uint(m));
  }
}

// ---------------- epilogue: out[b,f] = sum_q M[b,q]*W[q,f] + bias[f] ----------------
__global__ __launch_bounds__(192) void dense_kernel(const float* __restrict__ M,
                                                    const float* __restrict__ dw,
                                                    const float* __restrict__ db,
                                                    float* __restrict__ out) {
  const int t = threadIdx.x;
  if (t < NBS * 10) {
    const int b = t / 10, f = t - b * 10;
    float acc = db[f];
#pragma unroll
    for (int q = 0; q < 4; ++q) acc += M[b * 4 + q] * dw[q * 10 + f];
    out[t] = acc;
  }
}

extern "C" void kernel_launch(void* const* d_in, const int* in_sizes, int n_in,
                              void* d_out, int out_size, void* d_ws, size_t ws_size,
                              hipStream_t stream) {
  const float* x       = (const float*)d_in[0];  // (16, 8, 4096) f32
  const float* weights = (const float*)d_in[1];  // (3, 4) f32
  const float* dw      = (const float*)d_in[2];  // (4, 10) f32
  const float* db      = (const float*)d_in[3];  // (10,) f32
  float* out = (float*)d_out;                    // (16, 10) f32
  float* ws  = (float*)d_ws;

  setup_kernel<<<1, 64, 0, stream>>>(weights, ws);
  quanv_kernel<<<NBS * PB, 128, 0, stream>>>(x, ws, ws);
  dense_kernel<<<1, 192, 0, stream>>>(ws, dw, db, out);
}

// Round 3
// 30.639 us; speedup vs baseline: 1.4095x; 1.4095x over previous
//
#include <hip/hip_runtime.h>

// Problem constants (from reference)
#define LIN   4096
#define LOUT  4097          // (L + 2*PAD - KERNEL) + 1
#define NCH   8
#define NBS   16
#define POS_PER_BLK 32
#define PB    129           // ceil(LOUT / POS_PER_BLK)

// d_ws float layout:
//  [0..63]     M[b][q] atomic-max targets (relu'd -> uint order == float order)
//  [64..495]   C coefficients, padded: C[q][m][n12], q<4, m<9, n12<12 (n>=9 are 0)

// ---------------- register statevector sim (validated in R0/R1: absmax 0.0) ----------------
// State index: qubit j <-> bit (8 >> j); q0 is MSB (matches jnp C-order flatten).

template<int BIT>
__device__ __forceinline__ void apply_rx(float sr[16], float si[16], float c, float s) {
#pragma unroll
  for (int k = 0; k < 16; ++k) {
    if ((k & BIT) == 0) {
      const int a = k, b = k | BIT;
      const float ar = sr[a], ai = si[a], br = sr[b], bi = si[b];
      sr[a] = c * ar + s * bi;
      si[a] = c * ai - s * br;
      sr[b] = c * br + s * ai;
      si[b] = c * bi - s * ar;
    }
  }
}

template<int BIT>
__device__ __forceinline__ void apply_ry(float sr[16], float si[16], float c, float s) {
#pragma unroll
  for (int k = 0; k < 16; ++k) {
    if ((k & BIT) == 0) {
      const int a = k, b = k | BIT;
      const float ar = sr[a], ai = si[a], br = sr[b], bi = si[b];
      sr[a] = c * ar - s * br;
      si[a] = c * ai - s * bi;
      sr[b] = s * ar + c * br;
      si[b] = s * ai + c * bi;
    }
  }
}

template<int CBIT, int TBIT>
__device__ __forceinline__ void apply_cnot(float sr[16], float si[16]) {
#pragma unroll
  for (int k = 0; k < 16; ++k) {
    if ((k & CBIT) != 0 && (k & TBIT) == 0) {
      const int a = k, b = k | TBIT;
      float t;
      t = sr[a]; sr[a] = sr[b]; sr[b] = t;
      t = si[a]; si[a] = si[b]; si[b] = t;
    }
  }
}

__device__ __forceinline__ void basic_layer(float sr[16], float si[16],
                                            const float c[4], const float s[4]) {
  apply_rx<8>(sr, si, c[0], s[0]);
  apply_rx<4>(sr, si, c[1], s[1]);
  apply_rx<2>(sr, si, c[2], s[2]);
  apply_rx<1>(sr, si, c[3], s[3]);
  apply_cnot<8, 4>(sr, si);
  apply_cnot<4, 2>(sr, si);
  apply_cnot<2, 1>(sr, si);
  apply_cnot<1, 8>(sr, si);
}

// full circuit at window (w0, w1) -> ev[4]
__device__ void sim_circuit(const float* __restrict__ weights, float w0, float w1, float ev[4]) {
  float wc[3][4], wsn[3][4];
#pragma unroll
  for (int l = 0; l < 3; ++l)
#pragma unroll
    for (int q = 0; q < 4; ++q)
      __sincosf(weights[l * 4 + q] * 0.5f, &wsn[l][q], &wc[l][q]);

  float c0, s0, c1, s1;
  __sincosf(w0 * 0.5f, &s0, &c0);
  __sincosf(w1 * 0.5f, &s1, &c1);

  float sr[16], si[16];
#pragma unroll
  for (int k = 0; k < 16; ++k) { sr[k] = 0.0f; si[k] = 0.0f; }
  sr[0] = 1.0f;

  basic_layer(sr, si, wc[0], wsn[0]);
  apply_ry<8>(sr, si, c0, s0);
  apply_ry<4>(sr, si, c1, s1);
  apply_ry<2>(sr, si, c0, s0);
  apply_ry<1>(sr, si, c1, s1);
  basic_layer(sr, si, wc[1], wsn[1]);
  apply_ry<8>(sr, si, c0, s0);
  apply_ry<4>(sr, si, c1, s1);
  apply_ry<2>(sr, si, c0, s0);
  apply_ry<1>(sr, si, c1, s1);
  basic_layer(sr, si, wc[2], wsn[2]);

  float p[16];
#pragma unroll
  for (int k = 0; k < 16; ++k) p[k] = fmaf(sr[k], sr[k], si[k] * si[k]);

  float a1[8], ev3 = 0.0f;
#pragma unroll
  for (int k = 0; k < 8; ++k) {
    a1[k] = p[2 * k] + p[2 * k + 1];
    ev3 += p[2 * k] - p[2 * k + 1];
  }
  float a2[4], ev2 = 0.0f;
#pragma unroll
  for (int k = 0; k < 4; ++k) {
    a2[k] = a1[2 * k] + a1[2 * k + 1];
    ev2 += a1[2 * k] - a1[2 * k + 1];
  }
  ev[1] = (a2[0] - a2[1]) + (a2[2] - a2[3]);
  ev[0] = (a2[0] + a2[1]) - (a2[2] + a2[3]);
  ev[2] = ev2;
  ev[3] = ev3;
}

// ---------------- setup: fit ev_q(w0,w1) = u(w0)^T C_q u(w1), exact trig-poly ----------------
// basis f_0(w)=1, f_{2t-1}(w)=cos(t w), f_{2t}(w)=sin(t w), t=1..4  (9 funcs, exact deg-4)
__global__ __launch_bounds__(128) void setup_kernel(const float* __restrict__ weights,
                                                    float* __restrict__ ws) {
  __shared__ float E[4][81];   // ev_q at grid (j,k)
  __shared__ float fb[9][9];   // fb[m][j] = f_m(alpha_j)
  const int tid = threadIdx.x;
  if (tid < 64) ws[tid] = 0.0f;  // zero atomic-max targets

  const float alpha = 6.2831853071795864f / 9.0f;
  if (tid < 81) {
    const int j = tid / 9, k = tid % 9;
    float ev[4];
    sim_circuit(weights, alpha * (float)j, alpha * (float)k, ev);
#pragma unroll
    for (int q = 0; q < 4; ++q) E[q][tid] = ev[q];
    // fb[m][jj]: m = tid/9, jj = tid%9, frequency t = (m+1)/2
    const int m = j, jj = k;
    if (m == 0) {
      fb[0][jj] = 1.0f;
    } else {
      const int t = (m + 1) >> 1;
      float sv, cv;
      __sincosf(alpha * (float)(jj * t), &sv, &cv);
      fb[m][jj] = (m & 1) ? cv : sv;
    }
  }
  __syncthreads();

  // C_q[m][n] = (1/(d_m d_n)) * sum_{j,k} fb[m][j] fb[n][k] E_q[j][k]; pad n to 12
  for (int t = tid; t < 432; t += 128) {
    const int q = t / 108, r = t % 108, m = r / 12, n = r % 12;
    float val = 0.0f;
    if (n < 9) {
      float acc = 0.0f;
      for (int j = 0; j < 9; ++j) {
        float inner = 0.0f;
        for (int k = 0; k < 9; ++k) inner = fmaf(fb[n][k], E[q][j * 9 + k], inner);
        acc = fmaf(fb[m][j], inner, acc);
      }
      const float dm = (m == 0) ? 9.0f : 4.5f;
      const float dn = (n == 0) ? 9.0f : 4.5f;
      val = acc / (dm * dn);
    }
    ws[64 + t] = val;
  }
}

// build u(w) = [1, cos w, sin w, cos2w, sin2w, cos3w, sin3w, cos4w, sin4w]
__device__ __forceinline__ void build_u(float w, float u[9]) {
  float c, s;
  __sincosf(w, &s, &c);
  u[0] = 1.0f;
  u[1] = c;            u[2] = s;
  u[3] = fmaf(c, c, -(s * s));          // cos2
  u[4] = 2.0f * s * c;                  // sin2
  u[5] = fmaf(c, u[3], -(s * u[4]));    // cos3
  u[6] = fmaf(s, u[3], c * u[4]);       // sin3
  u[7] = fmaf(c, u[5], -(s * u[6]));    // cos4
  u[8] = fmaf(s, u[5], c * u[6]);       // sin4
}

// ---------------- main: one thread = one (b, ch, pos) window ----------------
__global__ __launch_bounds__(256) void quanv_kernel(const float* __restrict__ x,
                                                    const float* __restrict__ wsC,
                                                    float* __restrict__ wsM) {
  __shared__ float Msh[432];
  __shared__ float lmax[4][POS_PER_BLK];
  const int tid = threadIdx.x;
  for (int i = tid; i < 432; i += 256) Msh[i] = wsC[64 + i];

  const int blk = blockIdx.x;
  const int b   = blk / PB;
  const int pb  = blk - b * PB;
  const int ch  = tid & 7;
  const int grp = tid >> 3;                // 0..31
  const int pos = pb * POS_PER_BLK + grp;

  const float* row = x + (((size_t)b * NCH + ch) << 12);
  const float w0 = (pos >= 1 && pos <= LIN) ? row[pos - 1] : 0.0f;
  const float w1 = (pos < LIN) ? row[pos] : 0.0f;

  float u0[9], u1[9];
  build_u(w0, u0);
  build_u(w1, u1);

  __syncthreads();

  float ev[4];
#pragma unroll
  for (int q = 0; q < 4; ++q) {
    float acc = 0.0f;
#pragma unroll
    for (int m = 0; m < 9; ++m) {
      const float* rowp = Msh + q * 108 + m * 12;
      const float4 r0 = *(const float4*)(rowp);
      const float4 r1 = *(const float4*)(rowp + 4);
      const float  r8 = rowp[8];
      float d = r0.x * u1[0];
      d = fmaf(r0.y, u1[1], d);
      d = fmaf(r0.z, u1[2], d);
      d = fmaf(r0.w, u1[3], d);
      d = fmaf(r1.x, u1[4], d);
      d = fmaf(r1.y, u1[5], d);
      d = fmaf(r1.z, u1[6], d);
      d = fmaf(r1.w, u1[7], d);
      d = fmaf(r8,   u1[8], d);
      acc = fmaf(u0[m], d, acc);
    }
    ev[q] = acc;
  }

  // sum over channels: butterfly within 8-lane groups (tid = grp*8 + ch)
#pragma unroll
  for (int m = 1; m < 8; m <<= 1) {
#pragma unroll
    for (int q = 0; q < 4; ++q) ev[q] += __shfl_xor(ev[q], m, 64);
  }

  if (ch == 0) {
#pragma unroll
    for (int q = 0; q < 4; ++q)
      lmax[q][grp] = (pos < LOUT) ? fmaxf(ev[q], 0.0f) : 0.0f;
  }
  __syncthreads();
  if (tid < 4) {
    float m = 0.0f;
#pragma unroll
    for (int g = 0; g < POS_PER_BLK; ++g) m = fmaxf(m, lmax[tid][g]);
    atomicMax((unsigned int*)(wsM + b * 4 + tid), __float_as_uint(m));
  }
}

// ---------------- epilogue: out[b,f] = sum_q M[b,q]*W[q,f] + bias[f] ----------------
__global__ __launch_bounds__(192) void dense_kernel(const float* __restrict__ M,
                                                    const float* __restrict__ dw,
                                                    const float* __restrict__ db,
                                                    float* __restrict__ out) {
  const int t = threadIdx.x;
  if (t < NBS * 10) {
    const int b = t / 10, f = t - b * 10;
    float acc = db[f];
#pragma unroll
    for (int q = 0; q < 4; ++q) acc += M[b * 4 + q] * dw[q * 10 + f];
    out[t] = acc;
  }
}

extern "C" void kernel_launch(void* const* d_in, const int* in_sizes, int n_in,
                              void* d_out, int out_size, void* d_ws, size_t ws_size,
                              hipStream_t stream) {
  const float* x       = (const float*)d_in[0];  // (16, 8, 4096) f32
  const float* weights = (const float*)d_in[1];  // (3, 4) f32
  const float* dw      = (const float*)d_in[2];  // (4, 10) f32
  const float* db      = (const float*)d_in[3];  // (10,) f32
  float* out = (float*)d_out;                    // (16, 10) f32
  float* ws  = (float*)d_ws;

  setup_kernel<<<1, 128, 0, stream>>>(weights, ws);
  quanv_kernel<<<NBS * PB, 256, 0, stream>>>(x, ws, ws);
  dense_kernel<<<1, 192, 0, stream>>>(ws, dw, db, out);
}